// Round 1
// baseline (2723.024 us; speedup 1.0000x reference)
//
#include <hip/hip_runtime.h>
#include <hip/hip_bf16.h>

#define F 128
#define ET 7

typedef __attribute__((ext_vector_type(8))) short short8;
typedef __attribute__((ext_vector_type(4))) float f32x4;

static __device__ __forceinline__ unsigned short f2bf(float f) {
    unsigned u = __builtin_bit_cast(unsigned, f);
    unsigned r = u + 0x7fffu + ((u >> 16) & 1u);   // RTNE
    return (unsigned short)(r >> 16);
}
static __device__ __forceinline__ float bf2f(unsigned short h) {
    unsigned u = ((unsigned)h) << 16;
    return __builtin_bit_cast(float, u);
}

// Pre-pack W[i] (fp32 [K=128][O=128], k-major) into bf16 MFMA B-fragment lane
// order: for coltile c (0..7), kstep kk (0..3), lane l (0..63), elems e (0..7):
//   o = c*16 + (l&15);  k = kk*32 + 4*(l>>4) + (e&3) + 16*(e>>2)
__global__ __launch_bounds__(256) void prep_wfrag(const float* __restrict__ W,
                                                  unsigned short* __restrict__ Wfrag) {
    int tid = blockIdx.x * blockDim.x + threadIdx.x;
    if (tid >= ET * 2048) return;
    int i   = tid >> 11;
    int rem = tid & 2047;
    int c   = rem >> 8;
    int kk  = (rem >> 6) & 3;
    int l   = rem & 63;
    const float* Wi = W + (size_t)i * F * F;
    unsigned short* dst = Wfrag + (size_t)tid * 8;
    int o  = c * 16 + (l & 15);
    int kb = kk * 32 + 4 * (l >> 4);
#pragma unroll
    for (int e = 0; e < 8; ++e) {
        int k = kb + (e & 3) + 16 * (e >> 2);
        dst[e] = f2bf(Wi[k * F + o]);
    }
}

// h[r][o] = sum_k x[r][k] * W[k][o] + bias[o], written as bf16.
// Block = 256 thr (4 waves); wave covers 32 rows x 128 cols; block 128 rows.
__global__ __launch_bounds__(256) void gemm_h(const float* __restrict__ x,
                                              const unsigned short* __restrict__ Wfrag,
                                              const float* __restrict__ bias,
                                              unsigned short* __restrict__ hb,
                                              int M) {
    int wave = threadIdx.x >> 6;
    int lane = threadIdx.x & 63;
    int row_base = blockIdx.x * 128 + wave * 32;
    int lr = lane & 15;
    int lg = lane >> 4;     // 0..3

    f32x4 acc[2][8];
#pragma unroll
    for (int t = 0; t < 2; ++t)
#pragma unroll
        for (int c = 0; c < 8; ++c)
            acc[t][c] = (f32x4){0.f, 0.f, 0.f, 0.f};

#pragma unroll
    for (int kk = 0; kk < 4; ++kk) {
        int k0 = kk * 32 + 4 * lg;
        short8 afrag[2];
#pragma unroll
        for (int t = 0; t < 2; ++t) {
            int r = row_base + t * 16 + lr;
            r = r < M ? r : M - 1;                  // clamp tail (stores guarded)
            const float4* p0 = (const float4*)(x + (size_t)r * F + k0);
            const float4* p1 = (const float4*)(x + (size_t)r * F + k0 + 16);
            float4 v0 = *p0;
            float4 v1 = *p1;
            short8 a;
            a[0] = (short)f2bf(v0.x); a[1] = (short)f2bf(v0.y);
            a[2] = (short)f2bf(v0.z); a[3] = (short)f2bf(v0.w);
            a[4] = (short)f2bf(v1.x); a[5] = (short)f2bf(v1.y);
            a[6] = (short)f2bf(v1.z); a[7] = (short)f2bf(v1.w);
            afrag[t] = a;
        }
#pragma unroll
        for (int c = 0; c < 8; ++c) {
            short8 bfrag = *(const short8*)(Wfrag + (size_t)((c * 4 + kk) * 64 + lane) * 8);
            acc[0][c] = __builtin_amdgcn_mfma_f32_16x16x32_bf16(afrag[0], bfrag, acc[0][c], 0, 0, 0);
            acc[1][c] = __builtin_amdgcn_mfma_f32_16x16x32_bf16(afrag[1], bfrag, acc[1][c], 0, 0, 0);
        }
    }

    // C/D layout: col = lane&15, row = (lane>>4)*4 + j
#pragma unroll
    for (int c = 0; c < 8; ++c) {
        int o = c * 16 + lr;
        float bv = bias[o];
#pragma unroll
        for (int t = 0; t < 2; ++t) {
#pragma unroll
            for (int j = 0; j < 4; ++j) {
                int r = row_base + t * 16 + lg * 4 + j;
                if (r < M) hb[(size_t)r * F + o] = f2bf(acc[t][c][j] + bv);
            }
        }
    }
}

// One block per edge: out[b, start, f] += adj * h[b, end, f]  for b=0,1
__global__ __launch_bounds__(256) void edge_scatter(const unsigned short* __restrict__ hb,
                                                    const float* __restrict__ adj,
                                                    const int* __restrict__ endn,
                                                    const int* __restrict__ startn,
                                                    float* __restrict__ out,
                                                    int N, int E) {
    int e = blockIdx.x;
    if (e >= E) return;
    int b = threadIdx.x >> 7;
    int f = threadIdx.x & 127;
    float a = adj[e];
    int en = endn[e];
    int sn = startn[e];
    float v = a * bf2f(hb[((size_t)(b * N + en)) * F + f]);
    unsafeAtomicAdd(&out[((size_t)(b * N + sn)) * F + f], v);
}

// Fallback (only if ws too small): recompute projection per edge.
__global__ __launch_bounds__(256) void edge_fused_slow(const float* __restrict__ x,
                                                       const float* __restrict__ W,
                                                       const float* __restrict__ bias,
                                                       const float* __restrict__ adj,
                                                       const int* __restrict__ endn,
                                                       const int* __restrict__ startn,
                                                       float* __restrict__ out,
                                                       int N, int E) {
    __shared__ float xrow[2][F];
    int e = blockIdx.x;
    if (e >= E) return;
    int b = threadIdx.x >> 7;
    int f = threadIdx.x & 127;
    int en = endn[e], sn = startn[e];
    xrow[b][f] = x[((size_t)(b * N + en)) * F + f];
    __syncthreads();
    float acc = bias[f];
#pragma unroll 8
    for (int k = 0; k < F; ++k) acc += xrow[b][k] * W[k * F + f];
    unsafeAtomicAdd(&out[((size_t)(b * N + sn)) * F + f], adj[e] * acc);
}

extern "C" void kernel_launch(void* const* d_in, const int* in_sizes, int n_in,
                              void* d_out, int out_size, void* d_ws, size_t ws_size,
                              hipStream_t stream) {
    const float* x      = (const float*)d_in[0];
    const float* W      = (const float*)d_in[1];
    const float* bias   = (const float*)d_in[2];
    const float* adj    = (const float*)d_in[3];
    const int*   endn   = (const int*)d_in[4];
    const int*   startn = (const int*)d_in[5];

    const int B = 2;
    const int N = in_sizes[0] / (B * F);  // 100000
    const int E = in_sizes[3] / ET;       // 400000
    const int M = B * N;                  // 200000
    float* out = (float*)d_out;

    hipMemsetAsync(out, 0, (size_t)out_size * sizeof(float), stream);

    const size_t hb_off   = 256 * 1024;                            // Wfrag = 229 KB at ws+0
    const size_t hb_bytes = (size_t)M * F * sizeof(unsigned short); // 51.2 MB

    if (ws_size >= hb_off + hb_bytes) {
        unsigned short* Wfrag = (unsigned short*)d_ws;
        unsigned short* hb    = (unsigned short*)((char*)d_ws + hb_off);
        prep_wfrag<<<(ET * 2048 + 255) / 256, 256, 0, stream>>>(W, Wfrag);
        int ggrid = (M + 127) / 128;
        for (int i = 0; i < ET; ++i) {
            gemm_h<<<ggrid, 256, 0, stream>>>(x, Wfrag + (size_t)i * F * F, bias + i * F, hb, M);
            edge_scatter<<<E, 256, 0, stream>>>(hb, adj + (size_t)i * E, endn + (size_t)i * E,
                                                startn + (size_t)i * E, out, N, E);
        }
    } else {
        for (int i = 0; i < ET; ++i) {
            edge_fused_slow<<<E, 256, 0, stream>>>(x, W + (size_t)i * F * F, bias + i * F,
                                                   adj + (size_t)i * E, endn + (size_t)i * E,
                                                   startn + (size_t)i * E, out, N, E);
        }
    }
}

// Round 2
// 1325.488 us; speedup vs baseline: 2.0544x; 2.0544x over previous
//
#include <hip/hip_runtime.h>
#include <hip/hip_bf16.h>

#define F 128
#define ET 7

typedef __attribute__((ext_vector_type(8))) short short8;
typedef __attribute__((ext_vector_type(4))) float f32x4;

static __device__ __forceinline__ unsigned short f2bf(float f) {
    unsigned u = __builtin_bit_cast(unsigned, f);
    unsigned r = u + 0x7fffu + ((u >> 16) & 1u);   // RTNE
    return (unsigned short)(r >> 16);
}
static __device__ __forceinline__ float bf2f(unsigned short h) {
    unsigned u = ((unsigned)h) << 16;
    return __builtin_bit_cast(float, u);
}

// ---------------- GEMM part (unchanged from round 1, verified) ----------------

__global__ __launch_bounds__(256) void prep_wfrag(const float* __restrict__ W,
                                                  unsigned short* __restrict__ Wfrag) {
    int tid = blockIdx.x * blockDim.x + threadIdx.x;
    if (tid >= ET * 2048) return;
    int i   = tid >> 11;
    int rem = tid & 2047;
    int c   = rem >> 8;
    int kk  = (rem >> 6) & 3;
    int l   = rem & 63;
    const float* Wi = W + (size_t)i * F * F;
    unsigned short* dst = Wfrag + (size_t)tid * 8;
    int o  = c * 16 + (l & 15);
    int kb = kk * 32 + 4 * (l >> 4);
#pragma unroll
    for (int e = 0; e < 8; ++e) {
        int k = kb + (e & 3) + 16 * (e >> 2);
        dst[e] = f2bf(Wi[k * F + o]);
    }
}

__global__ __launch_bounds__(256) void gemm_h(const float* __restrict__ x,
                                              const unsigned short* __restrict__ Wfrag,
                                              const float* __restrict__ bias,
                                              unsigned short* __restrict__ hb,
                                              int M) {
    int wave = threadIdx.x >> 6;
    int lane = threadIdx.x & 63;
    int row_base = blockIdx.x * 128 + wave * 32;
    int lr = lane & 15;
    int lg = lane >> 4;

    f32x4 acc[2][8];
#pragma unroll
    for (int t = 0; t < 2; ++t)
#pragma unroll
        for (int c = 0; c < 8; ++c)
            acc[t][c] = (f32x4){0.f, 0.f, 0.f, 0.f};

#pragma unroll
    for (int kk = 0; kk < 4; ++kk) {
        int k0 = kk * 32 + 4 * lg;
        short8 afrag[2];
#pragma unroll
        for (int t = 0; t < 2; ++t) {
            int r = row_base + t * 16 + lr;
            r = r < M ? r : M - 1;
            const float4* p0 = (const float4*)(x + (size_t)r * F + k0);
            const float4* p1 = (const float4*)(x + (size_t)r * F + k0 + 16);
            float4 v0 = *p0;
            float4 v1 = *p1;
            short8 a;
            a[0] = (short)f2bf(v0.x); a[1] = (short)f2bf(v0.y);
            a[2] = (short)f2bf(v0.z); a[3] = (short)f2bf(v0.w);
            a[4] = (short)f2bf(v1.x); a[5] = (short)f2bf(v1.y);
            a[6] = (short)f2bf(v1.z); a[7] = (short)f2bf(v1.w);
            afrag[t] = a;
        }
#pragma unroll
        for (int c = 0; c < 8; ++c) {
            short8 bfrag = *(const short8*)(Wfrag + (size_t)((c * 4 + kk) * 64 + lane) * 8);
            acc[0][c] = __builtin_amdgcn_mfma_f32_16x16x32_bf16(afrag[0], bfrag, acc[0][c], 0, 0, 0);
            acc[1][c] = __builtin_amdgcn_mfma_f32_16x16x32_bf16(afrag[1], bfrag, acc[1][c], 0, 0, 0);
        }
    }

#pragma unroll
    for (int c = 0; c < 8; ++c) {
        int o = c * 16 + lr;
        float bv = bias[o];
#pragma unroll
        for (int t = 0; t < 2; ++t) {
#pragma unroll
            for (int j = 0; j < 4; ++j) {
                int r = row_base + t * 16 + lg * 4 + j;
                if (r < M) hb[(size_t)r * F + o] = f2bf(acc[t][c][j] + bv);
            }
        }
    }
}

// ---------------- CSR build ----------------
// counts/offsets/cursor are concatenated over (type, node): idx = i*N + n,
// length CN = 7*N. Sum of counts within a type == E, so a single global
// exclusive scan yields per-type-contiguous offsets automatically.

__global__ __launch_bounds__(256) void hist_kernel(const int* __restrict__ startn,
                                                   int* __restrict__ counts,
                                                   int N, int E, int totE) {
    int tid = blockIdx.x * 256 + threadIdx.x;
    if (tid >= totE) return;
    int i = tid / E;
    atomicAdd(&counts[i * N + startn[tid]], 1);
}

__global__ __launch_bounds__(256) void block_sum(const int* __restrict__ counts,
                                                 int* __restrict__ partials, int CN) {
    int gid = blockIdx.x * 256 + threadIdx.x;
    int v = gid < CN ? counts[gid] : 0;
#pragma unroll
    for (int off = 1; off < 64; off <<= 1) v += __shfl_xor(v, off);
    __shared__ int sh[4];
    if ((threadIdx.x & 63) == 0) sh[threadIdx.x >> 6] = v;
    __syncthreads();
    if (threadIdx.x == 0) partials[blockIdx.x] = sh[0] + sh[1] + sh[2] + sh[3];
}

__global__ __launch_bounds__(256) void scan_partials(int* __restrict__ partials, int nblk) {
    __shared__ int sh[256];
    int carry = 0;
    for (int base = 0; base < nblk; base += 256) {
        int idx = base + threadIdx.x;
        int v = idx < nblk ? partials[idx] : 0;
        __syncthreads();
        sh[threadIdx.x] = v;
        __syncthreads();
        for (int o = 1; o < 256; o <<= 1) {
            int t = (int)threadIdx.x >= o ? sh[threadIdx.x - o] : 0;
            __syncthreads();
            sh[threadIdx.x] += t;
            __syncthreads();
        }
        int incl = sh[threadIdx.x];
        int total = sh[255];
        if (idx < nblk) partials[idx] = incl - v + carry;
        carry += total;
    }
}

__global__ __launch_bounds__(256) void scan_blocks(const int* __restrict__ counts,
                                                   const int* __restrict__ partials,
                                                   int* __restrict__ offsets,
                                                   int* __restrict__ cursor,
                                                   int CN, int totE) {
    __shared__ int sh[256];
    int gid = blockIdx.x * 256 + threadIdx.x;
    int v = gid < CN ? counts[gid] : 0;
    sh[threadIdx.x] = v;
    __syncthreads();
    for (int o = 1; o < 256; o <<= 1) {
        int t = (int)threadIdx.x >= o ? sh[threadIdx.x - o] : 0;
        __syncthreads();
        sh[threadIdx.x] += t;
        __syncthreads();
    }
    int excl = sh[threadIdx.x] - v + partials[blockIdx.x];
    if (gid < CN) { offsets[gid] = excl; cursor[gid] = excl; }
    if (gid == CN - 1) offsets[CN] = totE;
}

__global__ __launch_bounds__(256) void fill_csr(const int* __restrict__ startn,
                                                const int* __restrict__ endn,
                                                const float* __restrict__ adj,
                                                int* __restrict__ cursor,
                                                int2* __restrict__ payload,
                                                int N, int E, int totE) {
    int tid = blockIdx.x * 256 + threadIdx.x;
    if (tid >= totE) return;
    int i = tid / E;
    int pos = atomicAdd(&cursor[i * N + startn[tid]], 1);
    payload[pos] = make_int2(endn[tid], __builtin_bit_cast(int, adj[tid]));
}

// ---------------- atomic-free gather: one block of 128 thr per start node ----
// thread = (batch b, f-pair j): reads uint (2 bf16) per edge, accumulates in
// registers, single non-atomic RMW of the output row (block owns node n).

__global__ __launch_bounds__(128) void node_gather(const unsigned short* __restrict__ h,
                                                   const int* __restrict__ offsets,
                                                   const int2* __restrict__ payload,
                                                   float* __restrict__ out,
                                                   int N, int ibase) {
    int n = blockIdx.x;
    int idx = ibase + n;
    int beg = offsets[idx];
    int end = offsets[idx + 1];
    int b = threadIdx.x >> 6;
    int f0 = (threadIdx.x & 63) * 2;
    const unsigned short* hb = h + (((size_t)b * N) << 7);
    float ax = 0.f, ay = 0.f;
    for (int k = beg; k < end; ++k) {
        int2 p = payload[k];
        float a = __builtin_bit_cast(float, p.y);
        unsigned v = *(const unsigned*)(hb + (((size_t)p.x) << 7) + f0);
        ax += a * bf2f((unsigned short)(v & 0xffffu));
        ay += a * bf2f((unsigned short)(v >> 16));
    }
    float2* op = (float2*)(out + ((((size_t)(b * N + n)) << 7) + f0));
    float2 cur = *op;
    cur.x += ax;
    cur.y += ay;
    *op = cur;
}

// ---------------- fallbacks (round-1 paths) ----------------

__global__ __launch_bounds__(256) void edge_scatter(const unsigned short* __restrict__ hb,
                                                    const float* __restrict__ adj,
                                                    const int* __restrict__ endn,
                                                    const int* __restrict__ startn,
                                                    float* __restrict__ out,
                                                    int N, int E) {
    int e = blockIdx.x;
    if (e >= E) return;
    int b = threadIdx.x >> 7;
    int f = threadIdx.x & 127;
    float a = adj[e];
    int en = endn[e];
    int sn = startn[e];
    float v = a * bf2f(hb[((size_t)(b * N + en)) * F + f]);
    unsafeAtomicAdd(&out[((size_t)(b * N + sn)) * F + f], v);
}

__global__ __launch_bounds__(256) void edge_fused_slow(const float* __restrict__ x,
                                                       const float* __restrict__ W,
                                                       const float* __restrict__ bias,
                                                       const float* __restrict__ adj,
                                                       const int* __restrict__ endn,
                                                       const int* __restrict__ startn,
                                                       float* __restrict__ out,
                                                       int N, int E) {
    __shared__ float xrow[2][F];
    int e = blockIdx.x;
    if (e >= E) return;
    int b = threadIdx.x >> 7;
    int f = threadIdx.x & 127;
    int en = endn[e], sn = startn[e];
    xrow[b][f] = x[((size_t)(b * N + en)) * F + f];
    __syncthreads();
    float acc = bias[f];
#pragma unroll 8
    for (int k = 0; k < F; ++k) acc += xrow[b][k] * W[k * F + f];
    unsafeAtomicAdd(&out[((size_t)(b * N + sn)) * F + f], adj[e] * acc);
}

// ---------------- launch ----------------

extern "C" void kernel_launch(void* const* d_in, const int* in_sizes, int n_in,
                              void* d_out, int out_size, void* d_ws, size_t ws_size,
                              hipStream_t stream) {
    const float* x      = (const float*)d_in[0];
    const float* W      = (const float*)d_in[1];
    const float* bias   = (const float*)d_in[2];
    const float* adj    = (const float*)d_in[3];
    const int*   endn   = (const int*)d_in[4];
    const int*   startn = (const int*)d_in[5];

    const int B = 2;
    const int N = in_sizes[0] / (B * F);  // 100000
    const int E = in_sizes[3] / ET;       // 400000
    const int M = B * N;                  // 200000
    const int totE = ET * E;              // 2.8M
    const int CN = ET * N;                // 700000
    const int nblk = (CN + 255) / 256;
    float* out = (float*)d_out;

    hipMemsetAsync(out, 0, (size_t)out_size * sizeof(float), stream);

    // ws layout (256B-aligned chunks)
    size_t off = 0;
    auto take = [&](size_t bytes) { size_t o = off; off = (off + bytes + 255) & ~(size_t)255; return o; };
    size_t o_wfrag    = take((size_t)ET * F * F * 2);
    size_t o_counts   = take((size_t)CN * 4);
    size_t o_offsets  = take((size_t)(CN + 1) * 4);
    size_t o_cursor   = take((size_t)CN * 4);
    size_t o_partials = take((size_t)nblk * 4);
    size_t o_payload  = take((size_t)totE * 8);
    size_t o_h        = take((size_t)M * F * 2);
    size_t need_new = off;
    size_t need_old = 256 * 1024 + (size_t)M * F * 2;

    if (ws_size >= need_new) {
        char* ws = (char*)d_ws;
        unsigned short* Wfrag = (unsigned short*)(ws + o_wfrag);
        int*  counts   = (int*)(ws + o_counts);
        int*  offsets  = (int*)(ws + o_offsets);
        int*  cursor   = (int*)(ws + o_cursor);
        int*  partials = (int*)(ws + o_partials);
        int2* payload  = (int2*)(ws + o_payload);
        unsigned short* hbuf = (unsigned short*)(ws + o_h);

        // CSR build (once)
        hipMemsetAsync(counts, 0, (size_t)CN * 4, stream);
        prep_wfrag<<<(ET * 2048 + 255) / 256, 256, 0, stream>>>(W, Wfrag);
        hist_kernel<<<(totE + 255) / 256, 256, 0, stream>>>(startn, counts, N, E, totE);
        block_sum<<<nblk, 256, 0, stream>>>(counts, partials, CN);
        scan_partials<<<1, 256, 0, stream>>>(partials, nblk);
        scan_blocks<<<nblk, 256, 0, stream>>>(counts, partials, offsets, cursor, CN, totE);
        fill_csr<<<(totE + 255) / 256, 256, 0, stream>>>(startn, endn, adj, cursor, payload, N, E, totE);

        int ggrid = (M + 127) / 128;
        for (int i = 0; i < ET; ++i) {
            gemm_h<<<ggrid, 256, 0, stream>>>(x, Wfrag + (size_t)i * F * F, bias + i * F, hbuf, M);
            node_gather<<<N, 128, 0, stream>>>(hbuf, offsets, payload, out, N, i * N);
        }
    } else if (ws_size >= need_old) {
        unsigned short* Wfrag = (unsigned short*)d_ws;
        unsigned short* hbuf  = (unsigned short*)((char*)d_ws + 256 * 1024);
        prep_wfrag<<<(ET * 2048 + 255) / 256, 256, 0, stream>>>(W, Wfrag);
        int ggrid = (M + 127) / 128;
        for (int i = 0; i < ET; ++i) {
            gemm_h<<<ggrid, 256, 0, stream>>>(x, Wfrag + (size_t)i * F * F, bias + i * F, hbuf, M);
            edge_scatter<<<E, 256, 0, stream>>>(hbuf, adj + (size_t)i * E, endn + (size_t)i * E,
                                                startn + (size_t)i * E, out, N, E);
        }
    } else {
        for (int i = 0; i < ET; ++i) {
            edge_fused_slow<<<E, 256, 0, stream>>>(x, W + (size_t)i * F * F, bias + i * F,
                                                   adj + (size_t)i * E, endn + (size_t)i * E,
                                                   startn + (size_t)i * E, out, N, E);
        }
    }
}

// Round 3
// 1156.658 us; speedup vs baseline: 2.3542x; 1.1460x over previous
//
#include <hip/hip_runtime.h>
#include <hip/hip_bf16.h>

#define F 128
#define ET 7
#define NT 32   // nodes per block in fused kernel

typedef __attribute__((ext_vector_type(8))) short short8;
typedef __attribute__((ext_vector_type(4))) float f32x4;
typedef __attribute__((ext_vector_type(4))) unsigned uint4v;

static __device__ __forceinline__ unsigned short f2bf(float f) {
    unsigned u = __builtin_bit_cast(unsigned, f);
    unsigned r = u + 0x7fffu + ((u >> 16) & 1u);   // RTNE
    return (unsigned short)(r >> 16);
}
static __device__ __forceinline__ float bf2f(unsigned short h) {
    unsigned u = ((unsigned)h) << 16;
    return __builtin_bit_cast(float, u);
}

// ---------------- W pre-pack into MFMA B-fragment order (verified r1) --------
__global__ __launch_bounds__(256) void prep_wfrag(const float* __restrict__ W,
                                                  unsigned short* __restrict__ Wfrag) {
    int tid = blockIdx.x * blockDim.x + threadIdx.x;
    if (tid >= ET * 2048) return;
    int i   = tid >> 11;
    int rem = tid & 2047;
    int c   = rem >> 8;
    int kk  = (rem >> 6) & 3;
    int l   = rem & 63;
    const float* Wi = W + (size_t)i * F * F;
    unsigned short* dst = Wfrag + (size_t)tid * 8;
    int o  = c * 16 + (l & 15);
    int kb = kk * 32 + 4 * (l >> 4);
#pragma unroll
    for (int e = 0; e < 8; ++e) {
        int k = kb + (e & 3) + 16 * (e >> 2);
        dst[e] = f2bf(Wi[k * F + o]);
    }
}

// ---------------- x -> bf16-packed copy (gather source, single 51MB buffer) --
__global__ __launch_bounds__(256) void xb_convert(const float* __restrict__ x,
                                                  unsigned* __restrict__ xb,
                                                  long n_pairs) {
    long stride = (long)gridDim.x * blockDim.x;
    for (long t = (long)blockIdx.x * blockDim.x + threadIdx.x; t < n_pairs; t += stride) {
        float2 v = ((const float2*)x)[t];
        xb[t] = (unsigned)f2bf(v.x) | ((unsigned)f2bf(v.y) << 16);
    }
}

// ---------------- CSR build (round-2 verified) -------------------------------
__global__ __launch_bounds__(256) void hist_kernel(const int* __restrict__ startn,
                                                   int* __restrict__ counts,
                                                   int N, int E, int totE) {
    int tid = blockIdx.x * 256 + threadIdx.x;
    if (tid >= totE) return;
    int i = tid / E;
    atomicAdd(&counts[i * N + startn[tid]], 1);
}

__global__ __launch_bounds__(256) void block_sum(const int* __restrict__ counts,
                                                 int* __restrict__ partials, int CN) {
    int gid = blockIdx.x * 256 + threadIdx.x;
    int v = gid < CN ? counts[gid] : 0;
#pragma unroll
    for (int off = 1; off < 64; off <<= 1) v += __shfl_xor(v, off);
    __shared__ int sh[4];
    if ((threadIdx.x & 63) == 0) sh[threadIdx.x >> 6] = v;
    __syncthreads();
    if (threadIdx.x == 0) partials[blockIdx.x] = sh[0] + sh[1] + sh[2] + sh[3];
}

__global__ __launch_bounds__(256) void scan_partials(int* __restrict__ partials, int nblk) {
    __shared__ int sh[256];
    int carry = 0;
    for (int base = 0; base < nblk; base += 256) {
        int idx = base + threadIdx.x;
        int v = idx < nblk ? partials[idx] : 0;
        __syncthreads();
        sh[threadIdx.x] = v;
        __syncthreads();
        for (int o = 1; o < 256; o <<= 1) {
            int t = (int)threadIdx.x >= o ? sh[threadIdx.x - o] : 0;
            __syncthreads();
            sh[threadIdx.x] += t;
            __syncthreads();
        }
        int incl = sh[threadIdx.x];
        int total = sh[255];
        if (idx < nblk) partials[idx] = incl - v + carry;
        carry += total;
    }
}

__global__ __launch_bounds__(256) void scan_blocks(const int* __restrict__ counts,
                                                   const int* __restrict__ partials,
                                                   int* __restrict__ offsets,
                                                   int* __restrict__ cursor,
                                                   int CN, int totE) {
    __shared__ int sh[256];
    int gid = blockIdx.x * 256 + threadIdx.x;
    int v = gid < CN ? counts[gid] : 0;
    sh[threadIdx.x] = v;
    __syncthreads();
    for (int o = 1; o < 256; o <<= 1) {
        int t = (int)threadIdx.x >= o ? sh[threadIdx.x - o] : 0;
        __syncthreads();
        sh[threadIdx.x] += t;
        __syncthreads();
    }
    int excl = sh[threadIdx.x] - v + partials[blockIdx.x];
    if (gid < CN) { offsets[gid] = excl; cursor[gid] = excl; }
    if (gid == CN - 1) offsets[CN] = totE;
}

__global__ __launch_bounds__(256) void fill_csr(const int* __restrict__ startn,
                                                const int* __restrict__ endn,
                                                const float* __restrict__ adj,
                                                int* __restrict__ cursor,
                                                int2* __restrict__ payload,
                                                int N, int E, int totE) {
    int tid = blockIdx.x * 256 + threadIdx.x;
    if (tid >= totE) return;
    int i = tid / E;
    int pos = atomicAdd(&cursor[i * N + startn[tid]], 1);
    payload[pos] = make_int2(endn[tid], __builtin_bit_cast(int, adj[tid]));
}

// ---------------- fused aggregate-then-project -------------------------------
// Block = 256 thr (4 waves), owns NT=32 nodes (64 output rows: b*32+nl).
// Per type i: wave w aggregates nodes [w*8, w*8+8) into bf16 y-tile in LDS
// (XOR-swizzled), then wave w runs MFMA on C-row-tile w (rows 16w..16w+16),
// accumulating into persistent acc. Epilogue adds sum(adj)*bias and stores.
__global__ __launch_bounds__(256) void fused_agg_gemm(
        const unsigned* __restrict__ xb,          // [2N][64] dwords (bf16x2)
        const unsigned short* __restrict__ Wfrag, // [7][2048][8]
        const float* __restrict__ bias,           // [7][128]
        const int* __restrict__ offsets,          // [7N+1]
        const int2* __restrict__ payload,         // [7E]
        float* __restrict__ out, int N) {
    __shared__ unsigned ylds[64 * 64];            // 64 rows x 64 dwords, swizzled
    __shared__ float sadjl[ET][NT];

    int wave = threadIdx.x >> 6;
    int lane = threadIdx.x & 63;
    int lr = lane & 15;
    int lg = lane >> 4;
    int n0 = blockIdx.x * NT;

    f32x4 acc[8];
#pragma unroll
    for (int c = 0; c < 8; ++c) acc[c] = (f32x4){0.f, 0.f, 0.f, 0.f};

    for (int i = 0; i < ET; ++i) {
        // ---- phase 1: aggregation (wave w -> nodes w*8 .. w*8+8) ----
#pragma unroll 1
        for (int q = 0; q < 8; ++q) {
            int nl = wave * 8 + q;
            int n  = n0 + nl;
            int beg = 0, end = 0;
            if (n < N) {
                int idx = i * N + n;
                beg = offsets[idx];
                end = offsets[idx + 1];
            }
            float a0x = 0.f, a0y = 0.f, a1x = 0.f, a1y = 0.f, asum = 0.f;
            for (int k = beg; k < end; ++k) {
                int2 p = payload[k];
                float a = __builtin_bit_cast(float, p.y);
                unsigned v0 = xb[((size_t)p.x << 6) + lane];
                unsigned v1 = xb[(((size_t)(N + p.x)) << 6) + lane];
                asum += a;
                a0x += a * bf2f((unsigned short)(v0 & 0xffffu));
                a0y += a * bf2f((unsigned short)(v0 >> 16));
                a1x += a * bf2f((unsigned short)(v1 & 0xffffu));
                a1y += a * bf2f((unsigned short)(v1 >> 16));
            }
            unsigned pk0 = (unsigned)f2bf(a0x) | ((unsigned)f2bf(a0y) << 16);
            unsigned pk1 = (unsigned)f2bf(a1x) | ((unsigned)f2bf(a1y) << 16);
            int r0 = nl;        // b=0 row
            int r1 = NT + nl;   // b=1 row
            ylds[(r0 * 64 + lane) ^ ((r0 & 7) << 1)] = pk0;
            ylds[(r1 * 64 + lane) ^ ((r1 & 7) << 1)] = pk1;
            if (lane == 0) sadjl[i][nl] = asum;
        }
        __syncthreads();
        // ---- phase 2: MFMA (wave w -> C rows 16w..16w+16) ----
        int row = wave * 16 + lr;
        int s = (row & 7) << 1;
#pragma unroll
        for (int kk = 0; kk < 4; ++kk) {
            int d0 = (row * 64 + kk * 16 + lg * 2) ^ s;
            int d1 = (row * 64 + kk * 16 + lg * 2 + 8) ^ s;
            uint2 c0 = *(const uint2*)&ylds[d0];
            uint2 c1 = *(const uint2*)&ylds[d1];
            uint4v av = {c0.x, c0.y, c1.x, c1.y};
            short8 afrag = __builtin_bit_cast(short8, av);
            const unsigned short* wb = Wfrag + ((size_t)i * 2048 + (size_t)kk * 64 + lane) * 8;
#pragma unroll
            for (int c = 0; c < 8; ++c) {
                short8 bfrag = *(const short8*)(wb + (size_t)c * 4 * 64 * 8);
                acc[c] = __builtin_amdgcn_mfma_f32_16x16x32_bf16(afrag, bfrag, acc[c], 0, 0, 0);
            }
        }
        __syncthreads();
    }

    // ---- epilogue: add sum(adj)*bias, store out once ----
#pragma unroll
    for (int c = 0; c < 8; ++c) {
        int col = c * 16 + lr;
        float bv[ET];
#pragma unroll
        for (int i = 0; i < ET; ++i) bv[i] = bias[i * F + col];
#pragma unroll
        for (int j = 0; j < 4; ++j) {
            int row_local = wave * 16 + lg * 4 + j;
            int nl = row_local & (NT - 1);
            int b  = row_local >> 5;
            int n  = n0 + nl;
            float v = acc[c][j];
#pragma unroll
            for (int i = 0; i < ET; ++i) v += sadjl[i][nl] * bv[i];
            if (n < N) out[((size_t)(b * N + n)) * F + col] = v;
        }
    }
}

// ---------------- fallbacks --------------------------------------------------
__global__ __launch_bounds__(256) void gemm_h(const float* __restrict__ x,
                                              const unsigned short* __restrict__ Wfrag,
                                              const float* __restrict__ bias,
                                              unsigned short* __restrict__ hb,
                                              int M) {
    int wave = threadIdx.x >> 6;
    int lane = threadIdx.x & 63;
    int row_base = blockIdx.x * 128 + wave * 32;
    int lr = lane & 15;
    int lg = lane >> 4;
    f32x4 acc[2][8];
#pragma unroll
    for (int t = 0; t < 2; ++t)
#pragma unroll
        for (int c = 0; c < 8; ++c)
            acc[t][c] = (f32x4){0.f, 0.f, 0.f, 0.f};
#pragma unroll
    for (int kk = 0; kk < 4; ++kk) {
        int k0 = kk * 32 + 4 * lg;
        short8 afrag[2];
#pragma unroll
        for (int t = 0; t < 2; ++t) {
            int r = row_base + t * 16 + lr;
            r = r < M ? r : M - 1;
            float4 v0 = *(const float4*)(x + (size_t)r * F + k0);
            float4 v1 = *(const float4*)(x + (size_t)r * F + k0 + 16);
            short8 a;
            a[0] = (short)f2bf(v0.x); a[1] = (short)f2bf(v0.y);
            a[2] = (short)f2bf(v0.z); a[3] = (short)f2bf(v0.w);
            a[4] = (short)f2bf(v1.x); a[5] = (short)f2bf(v1.y);
            a[6] = (short)f2bf(v1.z); a[7] = (short)f2bf(v1.w);
            afrag[t] = a;
        }
#pragma unroll
        for (int c = 0; c < 8; ++c) {
            short8 bfrag = *(const short8*)(Wfrag + (size_t)((c * 4 + kk) * 64 + lane) * 8);
            acc[0][c] = __builtin_amdgcn_mfma_f32_16x16x32_bf16(afrag[0], bfrag, acc[0][c], 0, 0, 0);
            acc[1][c] = __builtin_amdgcn_mfma_f32_16x16x32_bf16(afrag[1], bfrag, acc[1][c], 0, 0, 0);
        }
    }
#pragma unroll
    for (int c = 0; c < 8; ++c) {
        int o = c * 16 + lr;
        float bvv = bias[o];
#pragma unroll
        for (int t = 0; t < 2; ++t)
#pragma unroll
            for (int j = 0; j < 4; ++j) {
                int r = row_base + t * 16 + lg * 4 + j;
                if (r < M) hb[(size_t)r * F + o] = f2bf(acc[t][c][j] + bvv);
            }
    }
}

__global__ __launch_bounds__(256) void edge_scatter(const unsigned short* __restrict__ hb,
                                                    const float* __restrict__ adj,
                                                    const int* __restrict__ endn,
                                                    const int* __restrict__ startn,
                                                    float* __restrict__ out,
                                                    int N, int E) {
    int e = blockIdx.x;
    if (e >= E) return;
    int b = threadIdx.x >> 7;
    int f = threadIdx.x & 127;
    float a = adj[e];
    int en = endn[e];
    int sn = startn[e];
    float v = a * bf2f(hb[((size_t)(b * N + en)) * F + f]);
    unsafeAtomicAdd(&out[((size_t)(b * N + sn)) * F + f], v);
}

__global__ __launch_bounds__(256) void edge_fused_slow(const float* __restrict__ x,
                                                       const float* __restrict__ W,
                                                       const float* __restrict__ bias,
                                                       const float* __restrict__ adj,
                                                       const int* __restrict__ endn,
                                                       const int* __restrict__ startn,
                                                       float* __restrict__ out,
                                                       int N, int E) {
    __shared__ float xrow[2][F];
    int e = blockIdx.x;
    if (e >= E) return;
    int b = threadIdx.x >> 7;
    int f = threadIdx.x & 127;
    int en = endn[e], sn = startn[e];
    xrow[b][f] = x[((size_t)(b * N + en)) * F + f];
    __syncthreads();
    float acc = bias[f];
#pragma unroll 8
    for (int k = 0; k < F; ++k) acc += xrow[b][k] * W[k * F + f];
    unsafeAtomicAdd(&out[((size_t)(b * N + sn)) * F + f], adj[e] * acc);
}

// ---------------- launch -----------------------------------------------------
extern "C" void kernel_launch(void* const* d_in, const int* in_sizes, int n_in,
                              void* d_out, int out_size, void* d_ws, size_t ws_size,
                              hipStream_t stream) {
    const float* x      = (const float*)d_in[0];
    const float* W      = (const float*)d_in[1];
    const float* bias   = (const float*)d_in[2];
    const float* adj    = (const float*)d_in[3];
    const int*   endn   = (const int*)d_in[4];
    const int*   startn = (const int*)d_in[5];

    const int B = 2;
    const int N = in_sizes[0] / (B * F);  // 100000
    const int E = in_sizes[3] / ET;       // 400000
    const int M = B * N;                  // 200000
    const int totE = ET * E;              // 2.8M
    const int CN = ET * N;                // 700000
    const int nblk = (CN + 255) / 256;
    float* out = (float*)d_out;

    // ws layout (256B-aligned chunks)
    size_t off = 0;
    auto take = [&](size_t bytes) { size_t o = off; off = (off + bytes + 255) & ~(size_t)255; return o; };
    size_t o_wfrag    = take((size_t)ET * F * F * 2);
    size_t o_counts   = take((size_t)CN * 4);
    size_t o_offsets  = take((size_t)(CN + 1) * 4);
    size_t o_cursor   = take((size_t)CN * 4);
    size_t o_partials = take((size_t)nblk * 4);
    size_t o_payload  = take((size_t)totE * 8);
    size_t o_xb       = take((size_t)M * F * 2);
    size_t need_new = off;
    size_t need_old = 256 * 1024 + (size_t)M * F * 2;

    if (ws_size >= need_new) {
        char* ws = (char*)d_ws;
        unsigned short* Wfrag = (unsigned short*)(ws + o_wfrag);
        int*  counts   = (int*)(ws + o_counts);
        int*  offsets  = (int*)(ws + o_offsets);
        int*  cursor   = (int*)(ws + o_cursor);
        int*  partials = (int*)(ws + o_partials);
        int2* payload  = (int2*)(ws + o_payload);
        unsigned* xbuf = (unsigned*)(ws + o_xb);

        hipMemsetAsync(counts, 0, (size_t)CN * 4, stream);
        prep_wfrag<<<(ET * 2048 + 255) / 256, 256, 0, stream>>>(W, Wfrag);
        xb_convert<<<2048, 256, 0, stream>>>(x, xbuf, (long)M * (F / 2));
        hist_kernel<<<(totE + 255) / 256, 256, 0, stream>>>(startn, counts, N, E, totE);
        block_sum<<<nblk, 256, 0, stream>>>(counts, partials, CN);
        scan_partials<<<1, 256, 0, stream>>>(partials, nblk);
        scan_blocks<<<nblk, 256, 0, stream>>>(counts, partials, offsets, cursor, CN, totE);
        fill_csr<<<(totE + 255) / 256, 256, 0, stream>>>(startn, endn, adj, cursor, payload, N, E, totE);

        int fgrid = (N + NT - 1) / NT;   // 3125
        fused_agg_gemm<<<fgrid, 256, 0, stream>>>(xbuf, Wfrag, bias, offsets, payload, out, N);
    } else if (ws_size >= need_old) {
        hipMemsetAsync(out, 0, (size_t)out_size * sizeof(float), stream);
        unsigned short* Wfrag = (unsigned short*)d_ws;
        unsigned short* hbuf  = (unsigned short*)((char*)d_ws + 256 * 1024);
        prep_wfrag<<<(ET * 2048 + 255) / 256, 256, 0, stream>>>(W, Wfrag);
        int ggrid = (M + 127) / 128;
        for (int i = 0; i < ET; ++i) {
            gemm_h<<<ggrid, 256, 0, stream>>>(x, Wfrag + (size_t)i * F * F, bias + i * F, hbuf, M);
            edge_scatter<<<E, 256, 0, stream>>>(hbuf, adj + (size_t)i * E, endn + (size_t)i * E,
                                                startn + (size_t)i * E, out, N, E);
        }
    } else {
        hipMemsetAsync(out, 0, (size_t)out_size * sizeof(float), stream);
        for (int i = 0; i < ET; ++i) {
            edge_fused_slow<<<E, 256, 0, stream>>>(x, W + (size_t)i * F * F, bias + i * F,
                                                   adj + (size_t)i * E, endn + (size_t)i * E,
                                                   startn + (size_t)i * E, out, N, E);
        }
    }
}

// Round 4
// 861.331 us; speedup vs baseline: 3.1614x; 1.3429x over previous
//
#include <hip/hip_runtime.h>
#include <hip/hip_bf16.h>

#define F 128
#define ET 7
#define NT 32   // nodes per block in fused kernel

typedef __attribute__((ext_vector_type(8))) short short8;
typedef __attribute__((ext_vector_type(4))) float f32x4;
typedef __attribute__((ext_vector_type(4))) unsigned uint4v;

static __device__ __forceinline__ unsigned short f2bf(float f) {
    unsigned u = __builtin_bit_cast(unsigned, f);
    unsigned r = u + 0x7fffu + ((u >> 16) & 1u);   // RTNE
    return (unsigned short)(r >> 16);
}
static __device__ __forceinline__ float bf2f(unsigned short h) {
    unsigned u = ((unsigned)h) << 16;
    return __builtin_bit_cast(float, u);
}
static __device__ __forceinline__ float lo16(unsigned v) { return bf2f((unsigned short)(v & 0xffffu)); }
static __device__ __forceinline__ float hi16(unsigned v) { return bf2f((unsigned short)(v >> 16)); }

// ---------------- W pre-pack into MFMA B-fragment order (verified r1) --------
__global__ __launch_bounds__(256) void prep_wfrag(const float* __restrict__ W,
                                                  unsigned short* __restrict__ Wfrag) {
    int tid = blockIdx.x * blockDim.x + threadIdx.x;
    if (tid >= ET * 2048) return;
    int i   = tid >> 11;
    int rem = tid & 2047;
    int c   = rem >> 8;
    int kk  = (rem >> 6) & 3;
    int l   = rem & 63;
    const float* Wi = W + (size_t)i * F * F;
    unsigned short* dst = Wfrag + (size_t)tid * 8;
    int o  = c * 16 + (l & 15);
    int kb = kk * 32 + 4 * (l >> 4);
#pragma unroll
    for (int e = 0; e < 8; ++e) {
        int k = kb + (e & 3) + 16 * (e >> 2);
        dst[e] = f2bf(Wi[k * F + o]);
    }
}

// ---------------- x -> bf16-packed, batch-interleaved: xb[n][b][64] dwords ---
__global__ __launch_bounds__(256) void xb_convert(const float* __restrict__ x,
                                                  unsigned* __restrict__ xb,
                                                  int N, long n_pairs) {
    long stride = (long)gridDim.x * blockDim.x;
    for (long t = (long)blockIdx.x * blockDim.x + threadIdx.x; t < n_pairs; t += stride) {
        long row = t >> 6;          // source row = b*N + n
        int  c   = (int)(t & 63);
        int  b   = row >= N;
        long n   = row - (long)b * N;
        float2 v = ((const float2*)x)[t];
        xb[(n << 7) + b * 64 + c] = (unsigned)f2bf(v.x) | ((unsigned)f2bf(v.y) << 16);
    }
}

// ---------------- CSR build (round-2 verified) -------------------------------
__global__ __launch_bounds__(256) void hist_kernel(const int* __restrict__ startn,
                                                   int* __restrict__ counts,
                                                   int N, int E, int totE) {
    int tid = blockIdx.x * 256 + threadIdx.x;
    if (tid >= totE) return;
    int i = tid / E;
    atomicAdd(&counts[i * N + startn[tid]], 1);
}

__global__ __launch_bounds__(256) void block_sum(const int* __restrict__ counts,
                                                 int* __restrict__ partials, int CN) {
    int gid = blockIdx.x * 256 + threadIdx.x;
    int v = gid < CN ? counts[gid] : 0;
#pragma unroll
    for (int off = 1; off < 64; off <<= 1) v += __shfl_xor(v, off);
    __shared__ int sh[4];
    if ((threadIdx.x & 63) == 0) sh[threadIdx.x >> 6] = v;
    __syncthreads();
    if (threadIdx.x == 0) partials[blockIdx.x] = sh[0] + sh[1] + sh[2] + sh[3];
}

__global__ __launch_bounds__(256) void scan_partials(int* __restrict__ partials, int nblk) {
    __shared__ int sh[256];
    int carry = 0;
    for (int base = 0; base < nblk; base += 256) {
        int idx = base + threadIdx.x;
        int v = idx < nblk ? partials[idx] : 0;
        __syncthreads();
        sh[threadIdx.x] = v;
        __syncthreads();
        for (int o = 1; o < 256; o <<= 1) {
            int t = (int)threadIdx.x >= o ? sh[threadIdx.x - o] : 0;
            __syncthreads();
            sh[threadIdx.x] += t;
            __syncthreads();
        }
        int incl = sh[threadIdx.x];
        int total = sh[255];
        if (idx < nblk) partials[idx] = incl - v + carry;
        carry += total;
    }
}

__global__ __launch_bounds__(256) void scan_blocks(const int* __restrict__ counts,
                                                   const int* __restrict__ partials,
                                                   int* __restrict__ offsets,
                                                   int* __restrict__ cursor,
                                                   int CN, int totE) {
    __shared__ int sh[256];
    int gid = blockIdx.x * 256 + threadIdx.x;
    int v = gid < CN ? counts[gid] : 0;
    sh[threadIdx.x] = v;
    __syncthreads();
    for (int o = 1; o < 256; o <<= 1) {
        int t = (int)threadIdx.x >= o ? sh[threadIdx.x - o] : 0;
        __syncthreads();
        sh[threadIdx.x] += t;
        __syncthreads();
    }
    int excl = sh[threadIdx.x] - v + partials[blockIdx.x];
    if (gid < CN) { offsets[gid] = excl; cursor[gid] = excl; }
    if (gid == CN - 1) offsets[CN] = totE;
}

__global__ __launch_bounds__(256) void fill_csr(const int* __restrict__ startn,
                                                const int* __restrict__ endn,
                                                const float* __restrict__ adj,
                                                int* __restrict__ cursor,
                                                int2* __restrict__ payload,
                                                int N, int E, int totE) {
    int tid = blockIdx.x * 256 + threadIdx.x;
    if (tid >= totE) return;
    int i = tid / E;
    int pos = atomicAdd(&cursor[i * N + startn[tid]], 1);
    payload[pos] = make_int2(endn[tid], __builtin_bit_cast(int, adj[tid]));
}

// ---------------- fused aggregate-then-project -------------------------------
// Block = 512 thr (8 waves), owns NT=32 nodes (64 output rows).
// Per type i: waves dynamically grab nodes from an LDS ticket counter,
// aggregate that node's edges (2-edge unrolled: 4 gathers in flight) into a
// bf16 y-row in LDS (XOR-swizzled). Then MFMA: wave w -> C rows (w&3)*16..+15,
// col-tiles (w>>2)*4..+3, accumulating in persistent acc across all 7 types.
// Epilogue adds sum_i(sadj_i * bias_i) and stores out once.
__global__ __launch_bounds__(512, 4) void fused_agg_gemm(
        const unsigned* __restrict__ xb,          // [N][2][64] dwords (bf16x2)
        const unsigned short* __restrict__ Wfrag, // [7][2048][8]
        const float* __restrict__ bias,           // [7][128]
        const int* __restrict__ offsets,          // [7N+1]
        const int2* __restrict__ payload,         // [7E]
        float* __restrict__ out, int N) {
    __shared__ unsigned ylds[64 * 64];            // 64 rows x 64 dwords, swizzled
    __shared__ float sadjl[ET][NT];
    __shared__ int ticket[ET];

    int wave = threadIdx.x >> 6;
    int lane = threadIdx.x & 63;
    int lr = lane & 15;
    int lg = lane >> 4;
    int cb = (wave >> 2) * 4;      // col-tile base for MFMA phase
    int n0 = blockIdx.x * NT;

    if (threadIdx.x < ET) ticket[threadIdx.x] = 0;

    f32x4 acc[4];
#pragma unroll
    for (int c = 0; c < 4; ++c) acc[c] = (f32x4){0.f, 0.f, 0.f, 0.f};

    __syncthreads();

    for (int i = 0; i < ET; ++i) {
        // ---- phase 1: aggregation with dynamic node assignment ----
        for (;;) {
            int nl;
            if (lane == 0) nl = atomicAdd(&ticket[i], 1);
            nl = __shfl(nl, 0);
            if (nl >= NT) break;
            int n = n0 + nl;
            int beg = 0, end = 0;
            if (n < N) {
                int idx = i * N + n;
                beg = offsets[idx];
                end = offsets[idx + 1];
            }
            float a0x = 0.f, a0y = 0.f, a1x = 0.f, a1y = 0.f, asum = 0.f;
            int k = beg;
            for (; k + 2 <= end; k += 2) {
                int2 pA = payload[k];
                int2 pB = payload[k + 1];
                float aA = __builtin_bit_cast(float, pA.y);
                float aB = __builtin_bit_cast(float, pB.y);
                const unsigned* rA = xb + ((size_t)pA.x << 7);
                const unsigned* rB = xb + ((size_t)pB.x << 7);
                unsigned vA0 = rA[lane];
                unsigned vA1 = rA[64 + lane];
                unsigned vB0 = rB[lane];
                unsigned vB1 = rB[64 + lane];
                asum += aA + aB;
                a0x += aA * lo16(vA0) + aB * lo16(vB0);
                a0y += aA * hi16(vA0) + aB * hi16(vB0);
                a1x += aA * lo16(vA1) + aB * lo16(vB1);
                a1y += aA * hi16(vA1) + aB * hi16(vB1);
            }
            if (k < end) {
                int2 p = payload[k];
                float a = __builtin_bit_cast(float, p.y);
                const unsigned* r = xb + ((size_t)p.x << 7);
                unsigned v0 = r[lane];
                unsigned v1 = r[64 + lane];
                asum += a;
                a0x += a * lo16(v0);
                a0y += a * hi16(v0);
                a1x += a * lo16(v1);
                a1y += a * hi16(v1);
            }
            unsigned pk0 = (unsigned)f2bf(a0x) | ((unsigned)f2bf(a0y) << 16);
            unsigned pk1 = (unsigned)f2bf(a1x) | ((unsigned)f2bf(a1y) << 16);
            int r0 = nl;         // b=0 row
            int r1 = NT + nl;    // b=1 row
            ylds[(r0 * 64 + lane) ^ ((r0 & 7) << 1)] = pk0;
            ylds[(r1 * 64 + lane) ^ ((r1 & 7) << 1)] = pk1;
            if (lane == 0) sadjl[i][nl] = asum;
        }
        __syncthreads();
        // ---- phase 2: MFMA ----
        int row = (wave & 3) * 16 + lr;
        int s = (row & 7) << 1;
#pragma unroll
        for (int kk = 0; kk < 4; ++kk) {
            int d0 = (row * 64 + kk * 16 + lg * 2) ^ s;
            int d1 = (row * 64 + kk * 16 + lg * 2 + 8) ^ s;
            uint2 c0 = *(const uint2*)&ylds[d0];
            uint2 c1 = *(const uint2*)&ylds[d1];
            uint4v av = {c0.x, c0.y, c1.x, c1.y};
            short8 afrag = __builtin_bit_cast(short8, av);
            const unsigned short* wb = Wfrag + ((size_t)i * 2048 + (size_t)kk * 64 + lane) * 8;
#pragma unroll
            for (int c = 0; c < 4; ++c) {
                short8 bfrag = *(const short8*)(wb + (size_t)(cb + c) * 4 * 64 * 8);
                acc[c] = __builtin_amdgcn_mfma_f32_16x16x32_bf16(afrag, bfrag, acc[c], 0, 0, 0);
            }
        }
        __syncthreads();
    }

    // ---- epilogue: add sum(adj)*bias, store out once ----
#pragma unroll
    for (int c = 0; c < 4; ++c) {
        int col = (cb + c) * 16 + lr;
        float bv[ET];
#pragma unroll
        for (int i = 0; i < ET; ++i) bv[i] = bias[i * F + col];
#pragma unroll
        for (int j = 0; j < 4; ++j) {
            int row_local = (wave & 3) * 16 + lg * 4 + j;
            int nl = row_local & (NT - 1);
            int b  = row_local >> 5;
            int n  = n0 + nl;
            float v = acc[c][j];
#pragma unroll
            for (int i = 0; i < ET; ++i) v += sadjl[i][nl] * bv[i];
            if (n < N) out[((size_t)(b * N + n)) * F + col] = v;
        }
    }
}

// ---------------- fallbacks --------------------------------------------------
__global__ __launch_bounds__(256) void gemm_h(const float* __restrict__ x,
                                              const unsigned short* __restrict__ Wfrag,
                                              const float* __restrict__ bias,
                                              unsigned short* __restrict__ hb,
                                              int M) {
    int wave = threadIdx.x >> 6;
    int lane = threadIdx.x & 63;
    int row_base = blockIdx.x * 128 + wave * 32;
    int lr = lane & 15;
    int lg = lane >> 4;
    f32x4 acc[2][8];
#pragma unroll
    for (int t = 0; t < 2; ++t)
#pragma unroll
        for (int c = 0; c < 8; ++c)
            acc[t][c] = (f32x4){0.f, 0.f, 0.f, 0.f};
#pragma unroll
    for (int kk = 0; kk < 4; ++kk) {
        int k0 = kk * 32 + 4 * lg;
        short8 afrag[2];
#pragma unroll
        for (int t = 0; t < 2; ++t) {
            int r = row_base + t * 16 + lr;
            r = r < M ? r : M - 1;
            float4 v0 = *(const float4*)(x + (size_t)r * F + k0);
            float4 v1 = *(const float4*)(x + (size_t)r * F + k0 + 16);
            short8 a;
            a[0] = (short)f2bf(v0.x); a[1] = (short)f2bf(v0.y);
            a[2] = (short)f2bf(v0.z); a[3] = (short)f2bf(v0.w);
            a[4] = (short)f2bf(v1.x); a[5] = (short)f2bf(v1.y);
            a[6] = (short)f2bf(v1.z); a[7] = (short)f2bf(v1.w);
            afrag[t] = a;
        }
#pragma unroll
        for (int c = 0; c < 8; ++c) {
            short8 bfrag = *(const short8*)(Wfrag + (size_t)((c * 4 + kk) * 64 + lane) * 8);
            acc[0][c] = __builtin_amdgcn_mfma_f32_16x16x32_bf16(afrag[0], bfrag, acc[0][c], 0, 0, 0);
            acc[1][c] = __builtin_amdgcn_mfma_f32_16x16x32_bf16(afrag[1], bfrag, acc[1][c], 0, 0, 0);
        }
    }
#pragma unroll
    for (int c = 0; c < 8; ++c) {
        int o = c * 16 + lr;
        float bvv = bias[o];
#pragma unroll
        for (int t = 0; t < 2; ++t)
#pragma unroll
            for (int j = 0; j < 4; ++j) {
                int r = row_base + t * 16 + lg * 4 + j;
                if (r < M) hb[(size_t)r * F + o] = f2bf(acc[t][c][j] + bvv);
            }
    }
}

__global__ __launch_bounds__(256) void edge_scatter(const unsigned short* __restrict__ hb,
                                                    const float* __restrict__ adj,
                                                    const int* __restrict__ endn,
                                                    const int* __restrict__ startn,
                                                    float* __restrict__ out,
                                                    int N, int E) {
    int e = blockIdx.x;
    if (e >= E) return;
    int b = threadIdx.x >> 7;
    int f = threadIdx.x & 127;
    float a = adj[e];
    int en = endn[e];
    int sn = startn[e];
    float v = a * bf2f(hb[((size_t)(b * N + en)) * F + f]);
    unsafeAtomicAdd(&out[((size_t)(b * N + sn)) * F + f], v);
}

__global__ __launch_bounds__(256) void edge_fused_slow(const float* __restrict__ x,
                                                       const float* __restrict__ W,
                                                       const float* __restrict__ bias,
                                                       const float* __restrict__ adj,
                                                       const int* __restrict__ endn,
                                                       const int* __restrict__ startn,
                                                       float* __restrict__ out,
                                                       int N, int E) {
    __shared__ float xrow[2][F];
    int e = blockIdx.x;
    if (e >= E) return;
    int b = threadIdx.x >> 7;
    int f = threadIdx.x & 127;
    int en = endn[e], sn = startn[e];
    xrow[b][f] = x[((size_t)(b * N + en)) * F + f];
    __syncthreads();
    float acc = bias[f];
#pragma unroll 8
    for (int k = 0; k < F; ++k) acc += xrow[b][k] * W[k * F + f];
    unsafeAtomicAdd(&out[((size_t)(b * N + sn)) * F + f], adj[e] * acc);
}

// ---------------- launch -----------------------------------------------------
extern "C" void kernel_launch(void* const* d_in, const int* in_sizes, int n_in,
                              void* d_out, int out_size, void* d_ws, size_t ws_size,
                              hipStream_t stream) {
    const float* x      = (const float*)d_in[0];
    const float* W      = (const float*)d_in[1];
    const float* bias   = (const float*)d_in[2];
    const float* adj    = (const float*)d_in[3];
    const int*   endn   = (const int*)d_in[4];
    const int*   startn = (const int*)d_in[5];

    const int B = 2;
    const int N = in_sizes[0] / (B * F);  // 100000
    const int E = in_sizes[3] / ET;       // 400000
    const int M = B * N;                  // 200000
    const int totE = ET * E;              // 2.8M
    const int CN = ET * N;                // 700000
    const int nblk = (CN + 255) / 256;
    float* out = (float*)d_out;

    // ws layout (256B-aligned chunks)
    size_t off = 0;
    auto take = [&](size_t bytes) { size_t o = off; off = (off + bytes + 255) & ~(size_t)255; return o; };
    size_t o_wfrag    = take((size_t)ET * F * F * 2);
    size_t o_counts   = take((size_t)CN * 4);
    size_t o_offsets  = take((size_t)(CN + 1) * 4);
    size_t o_cursor   = take((size_t)CN * 4);
    size_t o_partials = take((size_t)nblk * 4);
    size_t o_payload  = take((size_t)totE * 8);
    size_t o_xb       = take((size_t)M * F * 2);
    size_t need_new = off;
    size_t need_old = 256 * 1024 + (size_t)M * F * 2;

    if (ws_size >= need_new) {
        char* ws = (char*)d_ws;
        unsigned short* Wfrag = (unsigned short*)(ws + o_wfrag);
        int*  counts   = (int*)(ws + o_counts);
        int*  offsets  = (int*)(ws + o_offsets);
        int*  cursor   = (int*)(ws + o_cursor);
        int*  partials = (int*)(ws + o_partials);
        int2* payload  = (int2*)(ws + o_payload);
        unsigned* xbuf = (unsigned*)(ws + o_xb);

        hipMemsetAsync(counts, 0, (size_t)CN * 4, stream);
        prep_wfrag<<<(ET * 2048 + 255) / 256, 256, 0, stream>>>(W, Wfrag);
        xb_convert<<<2048, 256, 0, stream>>>(x, xbuf, N, (long)M * (F / 2));
        hist_kernel<<<(totE + 255) / 256, 256, 0, stream>>>(startn, counts, N, E, totE);
        block_sum<<<nblk, 256, 0, stream>>>(counts, partials, CN);
        scan_partials<<<1, 256, 0, stream>>>(partials, nblk);
        scan_blocks<<<nblk, 256, 0, stream>>>(counts, partials, offsets, cursor, CN, totE);
        fill_csr<<<(totE + 255) / 256, 256, 0, stream>>>(startn, endn, adj, cursor, payload, N, E, totE);

        int fgrid = (N + NT - 1) / NT;   // 3125
        fused_agg_gemm<<<fgrid, 512, 0, stream>>>(xbuf, Wfrag, bias, offsets, payload, out, N);
    } else if (ws_size >= need_old) {
        hipMemsetAsync(out, 0, (size_t)out_size * sizeof(float), stream);
        unsigned short* Wfrag = (unsigned short*)d_ws;
        unsigned short* hbuf  = (unsigned short*)((char*)d_ws + 256 * 1024);
        prep_wfrag<<<(ET * 2048 + 255) / 256, 256, 0, stream>>>(W, Wfrag);
        int ggrid = (M + 127) / 128;
        for (int i = 0; i < ET; ++i) {
            gemm_h<<<ggrid, 256, 0, stream>>>(x, Wfrag + (size_t)i * F * F, bias + i * F, hbuf, M);
            edge_scatter<<<E, 256, 0, stream>>>(hbuf, adj + (size_t)i * E, endn + (size_t)i * E,
                                                startn + (size_t)i * E, out, N, E);
        }
    } else {
        hipMemsetAsync(out, 0, (size_t)out_size * sizeof(float), stream);
        for (int i = 0; i < ET; ++i) {
            edge_fused_slow<<<E, 256, 0, stream>>>(x, W + (size_t)i * F * F, bias + i * F,
                                                   adj + (size_t)i * E, endn + (size_t)i * E,
                                                   startn + (size_t)i * E, out, N, E);
        }
    }
}

// Round 5
// 799.027 us; speedup vs baseline: 3.4079x; 1.0780x over previous
//
#include <hip/hip_runtime.h>
#include <hip/hip_bf16.h>

#define F 128
#define ET 7
#define NT 32   // nodes per block in fused kernel

typedef __attribute__((ext_vector_type(8))) short short8;
typedef __attribute__((ext_vector_type(4))) float f32x4;
typedef __attribute__((ext_vector_type(4))) unsigned uint4v;

static __device__ __forceinline__ unsigned short f2bf(float f) {
    unsigned u = __builtin_bit_cast(unsigned, f);
    unsigned r = u + 0x7fffu + ((u >> 16) & 1u);   // RTNE
    return (unsigned short)(r >> 16);
}
static __device__ __forceinline__ float bf2f(unsigned short h) {
    unsigned u = ((unsigned)h) << 16;
    return __builtin_bit_cast(float, u);
}
static __device__ __forceinline__ float lo16(unsigned v) { return bf2f((unsigned short)(v & 0xffffu)); }
static __device__ __forceinline__ float hi16(unsigned v) { return bf2f((unsigned short)(v >> 16)); }

// ---------------- W pre-pack into MFMA B-fragment order (verified r1) --------
__global__ __launch_bounds__(256) void prep_wfrag(const float* __restrict__ W,
                                                  unsigned short* __restrict__ Wfrag) {
    int tid = blockIdx.x * blockDim.x + threadIdx.x;
    if (tid >= ET * 2048) return;
    int i   = tid >> 11;
    int rem = tid & 2047;
    int c   = rem >> 8;
    int kk  = (rem >> 6) & 3;
    int l   = rem & 63;
    const float* Wi = W + (size_t)i * F * F;
    unsigned short* dst = Wfrag + (size_t)tid * 8;
    int o  = c * 16 + (l & 15);
    int kb = kk * 32 + 4 * (l >> 4);
#pragma unroll
    for (int e = 0; e < 8; ++e) {
        int k = kb + (e & 3) + 16 * (e >> 2);
        dst[e] = f2bf(Wi[k * F + o]);
    }
}

// ---------------- x -> bf16-packed, batch-interleaved: xb[n][b][64] dwords ---
__global__ __launch_bounds__(256) void xb_convert(const float* __restrict__ x,
                                                  unsigned* __restrict__ xb,
                                                  int N, long n_pairs) {
    long stride = (long)gridDim.x * blockDim.x;
    for (long t = (long)blockIdx.x * blockDim.x + threadIdx.x; t < n_pairs; t += stride) {
        long row = t >> 6;          // source row = b*N + n
        int  c   = (int)(t & 63);
        int  b   = row >= N;
        long n   = row - (long)b * N;
        float2 v = ((const float2*)x)[t];
        xb[(n << 7) + b * 64 + c] = (unsigned)f2bf(v.x) | ((unsigned)f2bf(v.y) << 16);
    }
}

// ---------------- CSR build (round-2 verified) -------------------------------
__global__ __launch_bounds__(256) void hist_kernel(const int* __restrict__ startn,
                                                   int* __restrict__ counts,
                                                   int N, int E, int totE) {
    int tid = blockIdx.x * 256 + threadIdx.x;
    if (tid >= totE) return;
    int i = tid / E;
    atomicAdd(&counts[i * N + startn[tid]], 1);
}

__global__ __launch_bounds__(256) void block_sum(const int* __restrict__ counts,
                                                 int* __restrict__ partials, int CN) {
    int gid = blockIdx.x * 256 + threadIdx.x;
    int v = gid < CN ? counts[gid] : 0;
#pragma unroll
    for (int off = 1; off < 64; off <<= 1) v += __shfl_xor(v, off);
    __shared__ int sh[4];
    if ((threadIdx.x & 63) == 0) sh[threadIdx.x >> 6] = v;
    __syncthreads();
    if (threadIdx.x == 0) partials[blockIdx.x] = sh[0] + sh[1] + sh[2] + sh[3];
}

__global__ __launch_bounds__(256) void scan_partials(int* __restrict__ partials, int nblk) {
    __shared__ int sh[256];
    int carry = 0;
    for (int base = 0; base < nblk; base += 256) {
        int idx = base + threadIdx.x;
        int v = idx < nblk ? partials[idx] : 0;
        __syncthreads();
        sh[threadIdx.x] = v;
        __syncthreads();
        for (int o = 1; o < 256; o <<= 1) {
            int t = (int)threadIdx.x >= o ? sh[threadIdx.x - o] : 0;
            __syncthreads();
            sh[threadIdx.x] += t;
            __syncthreads();
        }
        int incl = sh[threadIdx.x];
        int total = sh[255];
        if (idx < nblk) partials[idx] = incl - v + carry;
        carry += total;
    }
}

__global__ __launch_bounds__(256) void scan_blocks(const int* __restrict__ counts,
                                                   const int* __restrict__ partials,
                                                   int* __restrict__ offsets,
                                                   int* __restrict__ cursor,
                                                   int CN, int totE) {
    __shared__ int sh[256];
    int gid = blockIdx.x * 256 + threadIdx.x;
    int v = gid < CN ? counts[gid] : 0;
    sh[threadIdx.x] = v;
    __syncthreads();
    for (int o = 1; o < 256; o <<= 1) {
        int t = (int)threadIdx.x >= o ? sh[threadIdx.x - o] : 0;
        __syncthreads();
        sh[threadIdx.x] += t;
        __syncthreads();
    }
    int excl = sh[threadIdx.x] - v + partials[blockIdx.x];
    if (gid < CN) { offsets[gid] = excl; cursor[gid] = excl; }
    if (gid == CN - 1) offsets[CN] = totE;
}

__global__ __launch_bounds__(256) void fill_csr(const int* __restrict__ startn,
                                                const int* __restrict__ endn,
                                                const float* __restrict__ adj,
                                                int* __restrict__ cursor,
                                                int2* __restrict__ payload,
                                                int N, int E, int totE) {
    int tid = blockIdx.x * 256 + threadIdx.x;
    if (tid >= totE) return;
    int i = tid / E;
    int pos = atomicAdd(&cursor[i * N + startn[tid]], 1);
    payload[pos] = make_int2(endn[tid], __builtin_bit_cast(int, adj[tid]));
}

// ---------------- fused aggregate-then-project -------------------------------
// Block = 512 thr (8 waves), owns NT=32 nodes (64 output rows).
// Aggregation: half-wave per edge — lanes 0-31 take even edges, 32-63 odd.
// Each half reads its edge's full 512B xb region (both batches) with ONE
// global_load_dwordx4 (16B/lane). 2-pair unroll keeps 2 KB in flight/wave.
// Side-combine via __shfl_xor(,32) once per node. bf16 y-tile in LDS with
// 16B-granule XOR swizzle ((r&7)<<2). MFMA: wave w -> C rows (w&3)*16..+15,
// col-tiles (w>>2)*4..+3, acc persistent across 7 types. Epilogue adds
// sum_i(sadj_i*bias_i), stores out once.
__global__ __launch_bounds__(512, 4) void fused_agg_gemm(
        const unsigned* __restrict__ xb,          // [N][2][64] dwords (bf16x2)
        const unsigned short* __restrict__ Wfrag, // [7][2048][8]
        const float* __restrict__ bias,           // [7][128]
        const int* __restrict__ offsets,          // [7N+1]
        const int2* __restrict__ payload,         // [7E]
        float* __restrict__ out, int N) {
    __shared__ unsigned ylds[64 * 64];            // 64 rows x 64 dwords, swizzled
    __shared__ float sadjl[ET][NT];
    __shared__ int ticket[ET];

    int wave = threadIdx.x >> 6;
    int lane = threadIdx.x & 63;
    int hl   = lane & 31;          // half-lane
    int side = lane >> 5;          // 0: even edges, 1: odd edges
    int lr = lane & 15;
    int lg = lane >> 4;
    int cb = (wave >> 2) * 4;      // col-tile base for MFMA phase
    int n0 = blockIdx.x * NT;

    if (threadIdx.x < ET) ticket[threadIdx.x] = 0;

    f32x4 acc[4];
#pragma unroll
    for (int c = 0; c < 4; ++c) acc[c] = (f32x4){0.f, 0.f, 0.f, 0.f};

    __syncthreads();

    for (int i = 0; i < ET; ++i) {
        // ---- phase 1: aggregation, dynamic node assignment ----
        for (;;) {
            int nl;
            if (lane == 0) nl = atomicAdd(&ticket[i], 1);
            nl = __shfl(nl, 0);
            if (nl >= NT) break;
            int n = n0 + nl;
            int beg = 0, end = 0;
            if (n < N) {
                int idx = i * N + n;
                beg = offsets[idx];
                end = offsets[idx + 1];
            }
            float a0 = 0.f, a1 = 0.f, a2 = 0.f, a3 = 0.f;
            float a4 = 0.f, a5 = 0.f, a6 = 0.f, a7 = 0.f;
            float asum = 0.f;
            int k = beg;
            // 2 pairs (4 edges) per iter: two independent 16B/lane chains
            for (; k + 4 <= end; k += 4) {
                int2 pA = payload[k + side];
                int2 pB = payload[k + 2 + side];
                float wA = __builtin_bit_cast(float, pA.y);
                float wB = __builtin_bit_cast(float, pB.y);
                uint4v vA = *(const uint4v*)(xb + ((size_t)pA.x << 7) + hl * 4);
                uint4v vB = *(const uint4v*)(xb + ((size_t)pB.x << 7) + hl * 4);
                asum += wA + wB;
                a0 += wA * lo16(vA[0]) + wB * lo16(vB[0]);
                a1 += wA * hi16(vA[0]) + wB * hi16(vB[0]);
                a2 += wA * lo16(vA[1]) + wB * lo16(vB[1]);
                a3 += wA * hi16(vA[1]) + wB * hi16(vB[1]);
                a4 += wA * lo16(vA[2]) + wB * lo16(vB[2]);
                a5 += wA * hi16(vA[2]) + wB * hi16(vB[2]);
                a6 += wA * lo16(vA[3]) + wB * lo16(vB[3]);
                a7 += wA * hi16(vA[3]) + wB * hi16(vB[3]);
            }
            for (; k + 2 <= end; k += 2) {
                int2 p = payload[k + side];
                float w = __builtin_bit_cast(float, p.y);
                uint4v v = *(const uint4v*)(xb + ((size_t)p.x << 7) + hl * 4);
                asum += w;
                a0 += w * lo16(v[0]); a1 += w * hi16(v[0]);
                a2 += w * lo16(v[1]); a3 += w * hi16(v[1]);
                a4 += w * lo16(v[2]); a5 += w * hi16(v[2]);
                a6 += w * lo16(v[3]); a7 += w * hi16(v[3]);
            }
            if (k < end && side == 0) {      // tail edge: half-wave 0 only
                int2 p = payload[k];
                float w = __builtin_bit_cast(float, p.y);
                uint4v v = *(const uint4v*)(xb + ((size_t)p.x << 7) + hl * 4);
                asum += w;
                a0 += w * lo16(v[0]); a1 += w * hi16(v[0]);
                a2 += w * lo16(v[1]); a3 += w * hi16(v[1]);
                a4 += w * lo16(v[2]); a5 += w * hi16(v[2]);
                a6 += w * lo16(v[3]); a7 += w * hi16(v[3]);
            }
            // ---- combine even/odd halves (all 64 lanes active) ----
            a0 += __shfl_xor(a0, 32); a1 += __shfl_xor(a1, 32);
            a2 += __shfl_xor(a2, 32); a3 += __shfl_xor(a3, 32);
            a4 += __shfl_xor(a4, 32); a5 += __shfl_xor(a5, 32);
            a6 += __shfl_xor(a6, 32); a7 += __shfl_xor(a7, 32);
            asum += __shfl_xor(asum, 32);
            // side 0 writes dwords {4hl,4hl+1}, side 1 writes {4hl+2,4hl+3}
            float s0 = side ? a4 : a0;
            float s1 = side ? a5 : a1;
            float s2 = side ? a6 : a2;
            float s3 = side ? a7 : a3;
            unsigned pk0 = (unsigned)f2bf(s0) | ((unsigned)f2bf(s1) << 16);
            unsigned pk1 = (unsigned)f2bf(s2) | ((unsigned)f2bf(s3) << 16);
            int d   = hl * 4 + side * 2;     // dword index in [0,128)
            int b   = d >> 6;
            int col = d & 63;
            int r   = b * NT + nl;
            *(uint2*)&ylds[(r * 64 + col) ^ ((r & 7) << 2)] = make_uint2(pk0, pk1);
            if (lane == 0) sadjl[i][nl] = asum;
        }
        __syncthreads();
        // ---- phase 2: MFMA ----
        int row = (wave & 3) * 16 + lr;
        int s = (row & 7) << 2;
#pragma unroll
        for (int kk = 0; kk < 4; ++kk) {
            int d0 = (row * 64 + kk * 16 + lg * 2) ^ s;
            int d1 = (row * 64 + kk * 16 + lg * 2 + 8) ^ s;
            uint2 c0 = *(const uint2*)&ylds[d0];
            uint2 c1 = *(const uint2*)&ylds[d1];
            uint4v av = {c0.x, c0.y, c1.x, c1.y};
            short8 afrag = __builtin_bit_cast(short8, av);
            const unsigned short* wb = Wfrag + ((size_t)i * 2048 + (size_t)kk * 64 + lane) * 8;
#pragma unroll
            for (int c = 0; c < 4; ++c) {
                short8 bfrag = *(const short8*)(wb + (size_t)(cb + c) * 4 * 64 * 8);
                acc[c] = __builtin_amdgcn_mfma_f32_16x16x32_bf16(afrag, bfrag, acc[c], 0, 0, 0);
            }
        }
        __syncthreads();
    }

    // ---- epilogue: add sum(adj)*bias, store out once ----
#pragma unroll
    for (int c = 0; c < 4; ++c) {
        int col = (cb + c) * 16 + lr;
        float bv[ET];
#pragma unroll
        for (int i = 0; i < ET; ++i) bv[i] = bias[i * F + col];
#pragma unroll
        for (int j = 0; j < 4; ++j) {
            int row_local = (wave & 3) * 16 + lg * 4 + j;
            int nl = row_local & (NT - 1);
            int b  = row_local >> 5;
            int n  = n0 + nl;
            float v = acc[c][j];
#pragma unroll
            for (int i = 0; i < ET; ++i) v += sadjl[i][nl] * bv[i];
            if (n < N) out[((size_t)(b * N + n)) * F + col] = v;
        }
    }
}

// ---------------- fallbacks --------------------------------------------------
__global__ __launch_bounds__(256) void gemm_h(const float* __restrict__ x,
                                              const unsigned short* __restrict__ Wfrag,
                                              const float* __restrict__ bias,
                                              unsigned short* __restrict__ hb,
                                              int M) {
    int wave = threadIdx.x >> 6;
    int lane = threadIdx.x & 63;
    int row_base = blockIdx.x * 128 + wave * 32;
    int lr = lane & 15;
    int lg = lane >> 4;
    f32x4 acc[2][8];
#pragma unroll
    for (int t = 0; t < 2; ++t)
#pragma unroll
        for (int c = 0; c < 8; ++c)
            acc[t][c] = (f32x4){0.f, 0.f, 0.f, 0.f};
#pragma unroll
    for (int kk = 0; kk < 4; ++kk) {
        int k0 = kk * 32 + 4 * lg;
        short8 afrag[2];
#pragma unroll
        for (int t = 0; t < 2; ++t) {
            int r = row_base + t * 16 + lr;
            r = r < M ? r : M - 1;
            float4 v0 = *(const float4*)(x + (size_t)r * F + k0);
            float4 v1 = *(const float4*)(x + (size_t)r * F + k0 + 16);
            short8 a;
            a[0] = (short)f2bf(v0.x); a[1] = (short)f2bf(v0.y);
            a[2] = (short)f2bf(v0.z); a[3] = (short)f2bf(v0.w);
            a[4] = (short)f2bf(v1.x); a[5] = (short)f2bf(v1.y);
            a[6] = (short)f2bf(v1.z); a[7] = (short)f2bf(v1.w);
            afrag[t] = a;
        }
#pragma unroll
        for (int c = 0; c < 8; ++c) {
            short8 bfrag = *(const short8*)(Wfrag + (size_t)((c * 4 + kk) * 64 + lane) * 8);
            acc[0][c] = __builtin_amdgcn_mfma_f32_16x16x32_bf16(afrag[0], bfrag, acc[0][c], 0, 0, 0);
            acc[1][c] = __builtin_amdgcn_mfma_f32_16x16x32_bf16(afrag[1], bfrag, acc[1][c], 0, 0, 0);
        }
    }
#pragma unroll
    for (int c = 0; c < 8; ++c) {
        int o = c * 16 + lr;
        float bvv = bias[o];
#pragma unroll
        for (int t = 0; t < 2; ++t)
#pragma unroll
            for (int j = 0; j < 4; ++j) {
                int r = row_base + t * 16 + lg * 4 + j;
                if (r < M) hb[(size_t)r * F + o] = f2bf(acc[t][c][j] + bvv);
            }
    }
}

__global__ __launch_bounds__(256) void edge_scatter(const unsigned short* __restrict__ hb,
                                                    const float* __restrict__ adj,
                                                    const int* __restrict__ endn,
                                                    const int* __restrict__ startn,
                                                    float* __restrict__ out,
                                                    int N, int E) {
    int e = blockIdx.x;
    if (e >= E) return;
    int b = threadIdx.x >> 7;
    int f = threadIdx.x & 127;
    float a = adj[e];
    int en = endn[e];
    int sn = startn[e];
    float v = a * bf2f(hb[((size_t)(b * N + en)) * F + f]);
    unsafeAtomicAdd(&out[((size_t)(b * N + sn)) * F + f], v);
}

__global__ __launch_bounds__(256) void edge_fused_slow(const float* __restrict__ x,
                                                       const float* __restrict__ W,
                                                       const float* __restrict__ bias,
                                                       const float* __restrict__ adj,
                                                       const int* __restrict__ endn,
                                                       const int* __restrict__ startn,
                                                       float* __restrict__ out,
                                                       int N, int E) {
    __shared__ float xrow[2][F];
    int e = blockIdx.x;
    if (e >= E) return;
    int b = threadIdx.x >> 7;
    int f = threadIdx.x & 127;
    int en = endn[e], sn = startn[e];
    xrow[b][f] = x[((size_t)(b * N + en)) * F + f];
    __syncthreads();
    float acc = bias[f];
#pragma unroll 8
    for (int k = 0; k < F; ++k) acc += xrow[b][k] * W[k * F + f];
    unsafeAtomicAdd(&out[((size_t)(b * N + sn)) * F + f], adj[e] * acc);
}

// ---------------- launch -----------------------------------------------------
extern "C" void kernel_launch(void* const* d_in, const int* in_sizes, int n_in,
                              void* d_out, int out_size, void* d_ws, size_t ws_size,
                              hipStream_t stream) {
    const float* x      = (const float*)d_in[0];
    const float* W      = (const float*)d_in[1];
    const float* bias   = (const float*)d_in[2];
    const float* adj    = (const float*)d_in[3];
    const int*   endn   = (const int*)d_in[4];
    const int*   startn = (const int*)d_in[5];

    const int B = 2;
    const int N = in_sizes[0] / (B * F);  // 100000
    const int E = in_sizes[3] / ET;       // 400000
    const int M = B * N;                  // 200000
    const int totE = ET * E;              // 2.8M
    const int CN = ET * N;                // 700000
    const int nblk = (CN + 255) / 256;
    float* out = (float*)d_out;

    // ws layout (256B-aligned chunks)
    size_t off = 0;
    auto take = [&](size_t bytes) { size_t o = off; off = (off + bytes + 255) & ~(size_t)255; return o; };
    size_t o_wfrag    = take((size_t)ET * F * F * 2);
    size_t o_counts   = take((size_t)CN * 4);
    size_t o_offsets  = take((size_t)(CN + 1) * 4);
    size_t o_cursor   = take((size_t)CN * 4);
    size_t o_partials = take((size_t)nblk * 4);
    size_t o_payload  = take((size_t)totE * 8);
    size_t o_xb       = take((size_t)M * F * 2);
    size_t need_new = off;
    size_t need_old = 256 * 1024 + (size_t)M * F * 2;

    if (ws_size >= need_new) {
        char* ws = (char*)d_ws;
        unsigned short* Wfrag = (unsigned short*)(ws + o_wfrag);
        int*  counts   = (int*)(ws + o_counts);
        int*  offsets  = (int*)(ws + o_offsets);
        int*  cursor   = (int*)(ws + o_cursor);
        int*  partials = (int*)(ws + o_partials);
        int2* payload  = (int2*)(ws + o_payload);
        unsigned* xbuf = (unsigned*)(ws + o_xb);

        hipMemsetAsync(counts, 0, (size_t)CN * 4, stream);
        prep_wfrag<<<(ET * 2048 + 255) / 256, 256, 0, stream>>>(W, Wfrag);
        xb_convert<<<2048, 256, 0, stream>>>(x, xbuf, N, (long)M * (F / 2));
        hist_kernel<<<(totE + 255) / 256, 256, 0, stream>>>(startn, counts, N, E, totE);
        block_sum<<<nblk, 256, 0, stream>>>(counts, partials, CN);
        scan_partials<<<1, 256, 0, stream>>>(partials, nblk);
        scan_blocks<<<nblk, 256, 0, stream>>>(counts, partials, offsets, cursor, CN, totE);
        fill_csr<<<(totE + 255) / 256, 256, 0, stream>>>(startn, endn, adj, cursor, payload, N, E, totE);

        int fgrid = (N + NT - 1) / NT;   // 3125
        fused_agg_gemm<<<fgrid, 512, 0, stream>>>(xbuf, Wfrag, bias, offsets, payload, out, N);
    } else if (ws_size >= need_old) {
        hipMemsetAsync(out, 0, (size_t)out_size * sizeof(float), stream);
        unsigned short* Wfrag = (unsigned short*)d_ws;
        unsigned short* hbuf  = (unsigned short*)((char*)d_ws + 256 * 1024);
        prep_wfrag<<<(ET * 2048 + 255) / 256, 256, 0, stream>>>(W, Wfrag);
        int ggrid = (M + 127) / 128;
        for (int i = 0; i < ET; ++i) {
            gemm_h<<<ggrid, 256, 0, stream>>>(x, Wfrag + (size_t)i * F * F, bias + i * F, hbuf, M);
            edge_scatter<<<E, 256, 0, stream>>>(hbuf, adj + (size_t)i * E, endn + (size_t)i * E,
                                                startn + (size_t)i * E, out, N, E);
        }
    } else {
        hipMemsetAsync(out, 0, (size_t)out_size * sizeof(float), stream);
        for (int i = 0; i < ET; ++i) {
            edge_fused_slow<<<E, 256, 0, stream>>>(x, W + (size_t)i * F * F, bias + i * F,
                                                   adj + (size_t)i * E, endn + (size_t)i * E,
                                                   startn + (size_t)i * E, out, N, E);
        }
    }
}